// Round 6
// baseline (191.614 us; speedup 1.0000x reference)
//
#include <hip/hip_runtime.h>
#include <math.h>

#define K_CODES 512
#define DIM 64
#define ROWS_PER_BLOCK 128   // old fallback kernel: 256 threads, 2 k-halves/row
#define BROWS 512            // mfma main: rows per block (2 groups x 8 waves x 32)
#define GROUPS 2

// ---------------------------------------------------------------------------
// Exact-arithmetic helpers (bit-match the verified round-1/2 kernels).
// ---------------------------------------------------------------------------
__device__ __forceinline__ float np_pairwise_sumsq(const float* v) {
#pragma clang fp contract(off)
    float p[DIM];
#pragma unroll
    for (int j = 0; j < DIM; ++j) p[j] = v[j] * v[j];
    float r[8];
#pragma unroll
    for (int a = 0; a < 8; ++a) r[a] = p[a];
#pragma unroll
    for (int i = 8; i < DIM; i += 8) {
#pragma unroll
        for (int a = 0; a < 8; ++a) r[a] = r[a] + p[i + a];
    }
    return ((r[0] + r[1]) + (r[2] + r[3])) + ((r[4] + r[5]) + (r[6] + r[7]));
}

__device__ __forceinline__ float np_dot8acc(const float* zr, const float* ck) {
#pragma clang fp contract(off)
    float a0 = 0.f, a1 = 0.f, a2 = 0.f, a3 = 0.f;
    float a4 = 0.f, a5 = 0.f, a6 = 0.f, a7 = 0.f;
#pragma unroll
    for (int j = 0; j < DIM; j += 8) {
        a0 = fmaf(zr[j + 0], ck[j + 0], a0);
        a1 = fmaf(zr[j + 1], ck[j + 1], a1);
        a2 = fmaf(zr[j + 2], ck[j + 2], a2);
        a3 = fmaf(zr[j + 3], ck[j + 3], a3);
        a4 = fmaf(zr[j + 4], ck[j + 4], a4);
        a5 = fmaf(zr[j + 5], ck[j + 5], a5);
        a6 = fmaf(zr[j + 6], ck[j + 6], a6);
        a7 = fmaf(zr[j + 7], ck[j + 7], a7);
    }
    return ((a0 + a1) + (a2 + a3)) + ((a4 + a5) + (a6 + a7));
}

// ---------------------------------------------------------------------------
// OLD KERNEL (verified, 176 us) — dispatch fallback if ws too small.
// ---------------------------------------------------------------------------
__global__ __launch_bounds__(256, 4) void vq_argmin_gather(
    const float* __restrict__ z, const float* __restrict__ cb,
    float* __restrict__ out, int n_rows) {
#pragma clang fp contract(off)
    __shared__ float esq_lds[K_CODES];
    __shared__ float red_d[ROWS_PER_BLOCK];
    __shared__ int   red_b[ROWS_PER_BLOCK];
    __shared__ int   best_lds[ROWS_PER_BLOCK];

    const int t = threadIdx.x;
    const int tr  = t & (ROWS_PER_BLOCK - 1);
    const int row = blockIdx.x * ROWS_PER_BLOCK + tr;
    const int k0 = __builtin_amdgcn_readfirstlane((t >> 7) << 8);

    float zr[DIM];
    const float4* zp = (const float4*)(z + (size_t)row * DIM);
#pragma unroll
    for (int j = 0; j < DIM / 4; ++j) {
        float4 v = zp[j];
        zr[4 * j + 0] = v.x; zr[4 * j + 1] = v.y;
        zr[4 * j + 2] = v.z; zr[4 * j + 3] = v.w;
    }
#pragma unroll
    for (int j = 0; j < DIM; ++j) { asm volatile("" : "+v"(zr[j])); }

    for (int c = t; c < K_CODES; c += 256)
        esq_lds[c] = np_pairwise_sumsq(cb + (size_t)c * DIM);
    __syncthreads();

    const float zsq = np_pairwise_sumsq(zr);
    float dmin = INFINITY;
    int best = k0;
    const float* __restrict__ cbase = cb + (size_t)k0 * DIM;
#pragma unroll 2
    for (int kk = 0; kk < K_CODES / 2; ++kk) {
        const float dot = np_dot8acc(zr, cbase + (size_t)kk * DIM);
        const float tkv = zsq + esq_lds[k0 + kk];
        const float m = 2.0f * dot;
        const float d = tkv - m;
        if (d < dmin) { dmin = d; best = k0 + kk; }
    }
    if (t >= ROWS_PER_BLOCK) { red_d[tr] = dmin; red_b[tr] = best; }
    __syncthreads();
    if (t < ROWS_PER_BLOCK) {
        int b = (red_d[tr] < dmin) ? red_b[tr] : best;
        best_lds[tr] = b;
    }
    __syncthreads();

    const float4* cb4 = (const float4*)cb;
    float4* o = (float4*)out;
    const size_t out1_off = (size_t)n_rows * (DIM / 4);
    const size_t grow = (size_t)blockIdx.x * ROWS_PER_BLOCK * (DIM / 4);
#pragma unroll
    for (int i = t; i < ROWS_PER_BLOCK * (DIM / 4); i += 256) {
        const int r = i >> 4;
        const int j = i & 15;
        const float4 v = cb4[(size_t)best_lds[r] * (DIM / 4) + j];
        const size_t g = grow + (size_t)r * (DIM / 4) + j;
        o[g] = v;
        o[g + out1_off] = v;
    }
}

// ---------------------------------------------------------------------------
// MFMA PATH. Round-6: 32x32x16 tiles (one wave covers 32 rows per B-stream
// -> LDS read volume per row halves; round-5 PMC put the LDS pipe at ~20 us
// of main's 60) and GROUPS=2 with grid=256 so the 128 KB B image is staged
// ONCE per CU (round-5 staged it 4x). Split numerics and EPS machinery are
// byte-identical to the absmax=0.0-verified rounds 2-5.
// ---------------------------------------------------------------------------
typedef __bf16 bfx8 __attribute__((ext_vector_type(8)));
typedef float  f32x16 __attribute__((ext_vector_type(16)));

#define EPS_GAP 3.0e-5f

// fp32 -> (hi bf16, lo bf16); x-hi exact (Sterbenz), lo = RN(residual).
__device__ __forceinline__ void split_bf16(float x, unsigned short& h, unsigned short& l) {
    unsigned int xb = __float_as_uint(x);
    unsigned int hb = (xb + 0x8000u) & 0xffff0000u;
    h = (unsigned short)(hb >> 16);
    float lf = x - __uint_as_float(hb);
    l = (unsigned short)((__float_as_uint(lf) + 0x8000u) >> 16);
}

// Prep: pack codebook into 32x32x16 B-fragment order (hi/lo) + np-order esq.
// Slot id = (tile*4 + kk)*64 + lane; elem j of lane l is
// cb[tile*32 + (l&31)][kk*16 + (l>>5)*8 + j].  16 tiles x 4 ksteps x 64 lanes.
// A and B use the SAME (lane,j)->k rule, so the MFMA dot is invariant to the
// HW's internal k ordering (the property that made the 16x16 layout work).
__global__ void vq_prep(const float* __restrict__ cb,
                        unsigned short* __restrict__ wh,
                        unsigned short* __restrict__ wl,
                        float* __restrict__ esq,
                        int* __restrict__ gcnt) {
    const int id = blockIdx.x * 256 + threadIdx.x;      // 0..4095
    if (id == 0) gcnt[0] = 0;
    const int l = id & 63;
    const int kk = (id >> 6) & 3;
    const int tile = id >> 8;
    const int code = tile * 32 + (l & 31);
    const int d0 = kk * 16 + (l >> 5) * 8;
    const float* p = cb + (size_t)code * DIM + d0;
    float4 v0 = *(const float4*)p;
    float4 v1 = *(const float4*)(p + 4);
    float f[8] = {v0.x, v0.y, v0.z, v0.w, v1.x, v1.y, v1.z, v1.w};
    union { unsigned short u[8]; uint4 q; } H, L;
#pragma unroll
    for (int j = 0; j < 8; ++j) split_bf16(f[j], H.u[j], L.u[j]);
    *(uint4*)(wh + (size_t)id * 8) = H.q;
    *(uint4*)(wl + (size_t)id * 8) = L.q;
    if (id < K_CODES) esq[id] = np_pairwise_sumsq(cb + (size_t)id * DIM);
}

// Main: 512 threads = 8 waves x 32 rows x 2 groups = 512 rows/block; grid 256
// (1 block/CU). B hi+lo staged once in 128 KB LDS. Live set ~150 VGPR
// (b1/b2/k1 48 + A 32 + acc 16 + B 32 transient + addr); waves_per_eu(1,2)
// is truthful (128 KB LDS caps at 1 block/CU = 2 waves/EU) -> 256-reg budget.
__global__ __launch_bounds__(512)
__attribute__((amdgpu_waves_per_eu(1, 2))) void vq_mfma_main(
    const float* __restrict__ z,
    const unsigned short* __restrict__ wfrag,   // hi 64KB || lo 64KB
    const float* __restrict__ esq_g,
    const float* __restrict__ cb,
    float* __restrict__ out,
    int* __restrict__ gcnt, int* __restrict__ grows,
    int n_rows) {
    __shared__ unsigned short b_lds[K_CODES * DIM * 2];  // 131072 B
    __shared__ float esq_lds[K_CODES];
    __shared__ int   best_lds[BROWS];

    const int t = threadIdx.x;
    const int wave = t >> 6;
    const int lane = t & 63;
    const int lc = lane & 31;      // code within tile / A row within group
    const int lh = lane >> 5;      // k-half selector
    const int rb = blockIdx.x * BROWS;

    // Stage the 128 KB fragment image once (16 x 8 KB cooperative copy).
    {
        const uint4* src = (const uint4*)wfrag;
        uint4* dst = (uint4*)b_lds;
#pragma unroll
        for (int i = 0; i < 16; ++i) dst[t + i * 512] = src[t + i * 512];
    }
    if (t < K_CODES) esq_lds[t] = esq_g[t];
    __syncthreads();   // b_lds + esq_lds ready

#pragma unroll 1
    for (int g = 0; g < GROUPS; ++g) {
        const int grb = rb + g * (BROWS / GROUPS) + wave * 32;

        // A fragments: z row (grb+lc) -> hi/lo bf16; k = kk*16 + lh*8 + j.
        bfx8 a_hi[4], a_lo[4];
#pragma unroll
        for (int kk = 0; kk < 4; ++kk) {
            const float* zp = z + (size_t)(grb + lc) * DIM + kk * 16 + lh * 8;
            float4 v0 = *(const float4*)zp;
            float4 v1 = *(const float4*)(zp + 4);
            float f[8] = {v0.x, v0.y, v0.z, v0.w, v1.x, v1.y, v1.z, v1.w};
            union { unsigned short u[8]; bfx8 b; } H, L;
#pragma unroll
            for (int j = 0; j < 8; ++j) split_bf16(f[j], H.u[j], L.u[j]);
            a_hi[kk] = H.b;
            a_lo[kk] = L.b;
        }

        float b1[16], b2[16];
        int   k1[16];
#pragma unroll
        for (int i = 0; i < 16; ++i) { b1[i] = INFINITY; b2[i] = INFINITY; k1[i] = 0; }

        for (int tt = 0; tt < 16; ++tt) {
            // B frags from LDS: lane-linear b128 reads (conflict-free, as r5).
            bfx8 bh[4], bl[4];
#pragma unroll
            for (int kk = 0; kk < 4; ++kk) {
                const int s = ((tt * 4 + kk) * 64 + lane) * 8;
                bh[kk] = *(const bfx8*)(b_lds + s);
                bl[kk] = *(const bfx8*)(b_lds + 32768 + s);
            }

            f32x16 acc = {0.f};
            // zh*eh (4 ksteps) + zh*el + zl*eh — same 3-term split as verified.
#pragma unroll
            for (int kk = 0; kk < 4; ++kk)
                acc = __builtin_amdgcn_mfma_f32_32x32x16_bf16(a_hi[kk], bh[kk], acc, 0, 0, 0);
#pragma unroll
            for (int kk = 0; kk < 4; ++kk)
                acc = __builtin_amdgcn_mfma_f32_32x32x16_bf16(a_hi[kk], bl[kk], acc, 0, 0, 0);
#pragma unroll
            for (int kk = 0; kk < 4; ++kk)
                acc = __builtin_amdgcn_mfma_f32_32x32x16_bf16(a_lo[kk], bh[kk], acc, 0, 0, 0);

            // D layout (m74/m101): col=lane&31 (the code), row=(r&3)+8*(r>>2)+4*lh.
            const float ev = esq_lds[tt * 32 + lc];
            const int   kc = tt * 32 + lc;
#pragma unroll
            for (int r = 0; r < 16; ++r) {
                float s = fmaf(-2.0f, acc[r], ev);       // row-constant zsq dropped
                b2[r] = fminf(fmaxf(s, b1[r]), b2[r]);   // second-best update
                bool c = s < b1[r];
                b1[r] = c ? s : b1[r];
                k1[r] = c ? kc : k1[r];
            }
        }

        // Reduce across the 32 code-lanes (masks <32 keep lh fixed).
#pragma unroll
        for (int m = 1; m <= 16; m <<= 1) {
#pragma unroll
            for (int r = 0; r < 16; ++r) {
                float ob1 = __shfl_xor(b1[r], m);
                int   ok1 = __shfl_xor(k1[r], m);
                float ob2 = __shfl_xor(b2[r], m);
                float nb2 = fminf(fmaxf(b1[r], ob1), fminf(b2[r], ob2));
                bool take = (ob1 < b1[r]) || (ob1 == b1[r] && ok1 < k1[r]);
                b1[r] = take ? ob1 : b1[r];
                k1[r] = take ? ok1 : k1[r];
                b2[r] = nb2;
            }
        }

        // Publish (lanes 0 and 32 each own 16 distinct rows); flag near-ties.
        if (lc == 0) {
#pragma unroll
            for (int r = 0; r < 16; ++r) {
                const int rl = g * (BROWS / GROUPS) + wave * 32
                             + (r & 3) + 8 * (r >> 2) + 4 * lh;
                best_lds[rl] = k1[r];
                if (b2[r] - b1[r] <= EPS_GAP) {
                    int p = atomicAdd(gcnt, 1);
                    grows[p] = rb + rl;
                }
            }
        }
    }
    __syncthreads();

    // Block-cooperative coalesced gather + dual write (verified pattern).
    const float4* cb4 = (const float4*)cb;
    float4* o = (float4*)out;
    const size_t out1_off = (size_t)n_rows * (DIM / 4);
    const size_t grow = (size_t)blockIdx.x * BROWS * (DIM / 4);
#pragma unroll
    for (int i = t; i < BROWS * (DIM / 4); i += 512) {
        const int r = i >> 4;
        const int j = i & 15;
        const float4 v = cb4[(size_t)best_lds[r] * (DIM / 4) + j];
        const size_t g = grow + (size_t)r * (DIM / 4) + j;
        o[g] = v;
        o[g + out1_off] = v;
    }
}

// Fixup (verified round-5 config): one wave per flagged row; wave-uniform
// scalar z loads; bit-identical np arithmetic; overwrites solved rows.
__global__ __launch_bounds__(256, 1) void vq_fixup(
    const float* __restrict__ z, const float* __restrict__ cb,
    const float* __restrict__ esq_g,
    const int* __restrict__ gcnt, const int* __restrict__ grows,
    float* __restrict__ out, int n_rows) {
#pragma clang fp contract(off)
    const int lane = threadIdx.x & 63;
    const int wid = (blockIdx.x * 256 + threadIdx.x) >> 6;   // 0..1023
    const int nf = gcnt[0];

    for (int fi = wid; fi < nf; fi += 1024) {
        const int row = __builtin_amdgcn_readfirstlane(grows[fi]);
        const float* zp = z + (size_t)row * DIM;
        float zs[DIM];
#pragma unroll
        for (int j = 0; j < DIM; ++j) zs[j] = zp[j];

        const float zsq = np_pairwise_sumsq(zs);
        float dmin = INFINITY;
        int bk = lane * 8;
        const float* cbase = cb + (size_t)(lane * 8) * DIM;
#pragma unroll
        for (int c = 0; c < 8; ++c) {
            const float dot = np_dot8acc(zs, cbase + (size_t)c * DIM);
            const float tkv = zsq + esq_g[lane * 8 + c];
            const float m2 = 2.0f * dot;
            const float d = tkv - m2;
            if (d < dmin) { dmin = d; bk = lane * 8 + c; }
        }
#pragma unroll
        for (int m = 1; m <= 32; m <<= 1) {
            float od = __shfl_xor(dmin, m);
            int   ob = __shfl_xor(bk, m);
            bool take = (od < dmin) || (od == dmin && ob < bk);
            dmin = take ? od : dmin;
            bk = take ? ob : bk;
        }
        if (lane < 16) {
            const float4 v = ((const float4*)cb)[(size_t)bk * (DIM / 4) + lane];
            float4* o = (float4*)out;
            const size_t g = (size_t)row * (DIM / 4) + lane;
            o[g] = v;
            o[g + (size_t)n_rows * (DIM / 4)] = v;
        }
    }
}

// ---------------------------------------------------------------------------
extern "C" void kernel_launch(void* const* d_in, const int* in_sizes, int n_in,
                              void* d_out, int out_size, void* d_ws, size_t ws_size,
                              hipStream_t stream) {
    const float* z  = (const float*)d_in[0];   // [N, 64] fp32
    const float* cb = (const float*)d_in[1];   // [512, 64] fp32
    float* out = (float*)d_out;                // [2 * N * 64] fp32

    const int n_rows = in_sizes[0] / DIM;      // 131072

    // ws layout: wh 64KB | wl 64KB | esq 2KB | gcnt 16B | grows n_rows*4B
    const size_t frag_elems = (size_t)K_CODES * DIM;           // 32768 shorts
    const size_t WS_NEED = frag_elems * 2 * 2 + K_CODES * 4 + 16 + (size_t)n_rows * 4;
    if (ws_size >= WS_NEED && (n_rows % BROWS) == 0) {
        unsigned short* wh = (unsigned short*)d_ws;
        unsigned short* wl = wh + frag_elems;
        float* esq = (float*)(wl + frag_elems);
        int* gcnt  = (int*)(esq + K_CODES);
        int* grows = gcnt + 4;
        vq_prep<<<dim3(16), dim3(256), 0, stream>>>(cb, wh, wl, esq, gcnt);
        vq_mfma_main<<<dim3(n_rows / BROWS), dim3(512), 0, stream>>>(
            z, wh, esq, cb, out, gcnt, grows, n_rows);
        vq_fixup<<<dim3(256), dim3(256), 0, stream>>>(
            z, cb, esq, gcnt, grows, out, n_rows);
    } else {
        vq_argmin_gather<<<dim3(n_rows / ROWS_PER_BLOCK), dim3(256), 0, stream>>>(
            z, cb, out, n_rows);
    }
}

// Round 7
// 161.049 us; speedup vs baseline: 1.1898x; 1.1898x over previous
//
#include <hip/hip_runtime.h>
#include <math.h>

#define K_CODES 512
#define DIM 64
#define ROWS_PER_BLOCK 128   // old fallback kernel: 256 threads, 2 k-halves/row
#define BROWS 512            // mfma main: rows/block = 2 groups x 8 waves x 32
#define GROUPS 2

// ---------------------------------------------------------------------------
// Exact-arithmetic helpers (bit-match the verified round-1/2 kernels).
// ---------------------------------------------------------------------------
__device__ __forceinline__ float np_pairwise_sumsq(const float* v) {
#pragma clang fp contract(off)
    float p[DIM];
#pragma unroll
    for (int j = 0; j < DIM; ++j) p[j] = v[j] * v[j];
    float r[8];
#pragma unroll
    for (int a = 0; a < 8; ++a) r[a] = p[a];
#pragma unroll
    for (int i = 8; i < DIM; i += 8) {
#pragma unroll
        for (int a = 0; a < 8; ++a) r[a] = r[a] + p[i + a];
    }
    return ((r[0] + r[1]) + (r[2] + r[3])) + ((r[4] + r[5]) + (r[6] + r[7]));
}

__device__ __forceinline__ float np_dot8acc(const float* zr, const float* ck) {
#pragma clang fp contract(off)
    float a0 = 0.f, a1 = 0.f, a2 = 0.f, a3 = 0.f;
    float a4 = 0.f, a5 = 0.f, a6 = 0.f, a7 = 0.f;
#pragma unroll
    for (int j = 0; j < DIM; j += 8) {
        a0 = fmaf(zr[j + 0], ck[j + 0], a0);
        a1 = fmaf(zr[j + 1], ck[j + 1], a1);
        a2 = fmaf(zr[j + 2], ck[j + 2], a2);
        a3 = fmaf(zr[j + 3], ck[j + 3], a3);
        a4 = fmaf(zr[j + 4], ck[j + 4], a4);
        a5 = fmaf(zr[j + 5], ck[j + 5], a5);
        a6 = fmaf(zr[j + 6], ck[j + 6], a6);
        a7 = fmaf(zr[j + 7], ck[j + 7], a7);
    }
    return ((a0 + a1) + (a2 + a3)) + ((a4 + a5) + (a6 + a7));
}

// ---------------------------------------------------------------------------
// OLD KERNEL (verified, 176 us) — dispatch fallback if ws too small.
// ---------------------------------------------------------------------------
__global__ __launch_bounds__(256, 4) void vq_argmin_gather(
    const float* __restrict__ z, const float* __restrict__ cb,
    float* __restrict__ out, int n_rows) {
#pragma clang fp contract(off)
    __shared__ float esq_lds[K_CODES];
    __shared__ float red_d[ROWS_PER_BLOCK];
    __shared__ int   red_b[ROWS_PER_BLOCK];
    __shared__ int   best_lds[ROWS_PER_BLOCK];

    const int t = threadIdx.x;
    const int tr  = t & (ROWS_PER_BLOCK - 1);
    const int row = blockIdx.x * ROWS_PER_BLOCK + tr;
    const int k0 = __builtin_amdgcn_readfirstlane((t >> 7) << 8);

    float zr[DIM];
    const float4* zp = (const float4*)(z + (size_t)row * DIM);
#pragma unroll
    for (int j = 0; j < DIM / 4; ++j) {
        float4 v = zp[j];
        zr[4 * j + 0] = v.x; zr[4 * j + 1] = v.y;
        zr[4 * j + 2] = v.z; zr[4 * j + 3] = v.w;
    }
#pragma unroll
    for (int j = 0; j < DIM; ++j) { asm volatile("" : "+v"(zr[j])); }

    for (int c = t; c < K_CODES; c += 256)
        esq_lds[c] = np_pairwise_sumsq(cb + (size_t)c * DIM);
    __syncthreads();

    const float zsq = np_pairwise_sumsq(zr);
    float dmin = INFINITY;
    int best = k0;
    const float* __restrict__ cbase = cb + (size_t)k0 * DIM;
#pragma unroll 2
    for (int kk = 0; kk < K_CODES / 2; ++kk) {
        const float dot = np_dot8acc(zr, cbase + (size_t)kk * DIM);
        const float tkv = zsq + esq_lds[k0 + kk];
        const float m = 2.0f * dot;
        const float d = tkv - m;
        if (d < dmin) { dmin = d; best = k0 + kk; }
    }
    if (t >= ROWS_PER_BLOCK) { red_d[tr] = dmin; red_b[tr] = best; }
    __syncthreads();
    if (t < ROWS_PER_BLOCK) {
        int b = (red_d[tr] < dmin) ? red_b[tr] : best;
        best_lds[tr] = b;
    }
    __syncthreads();

    const float4* cb4 = (const float4*)cb;
    float4* o = (float4*)out;
    const size_t out1_off = (size_t)n_rows * (DIM / 4);
    const size_t grow = (size_t)blockIdx.x * ROWS_PER_BLOCK * (DIM / 4);
#pragma unroll
    for (int i = t; i < ROWS_PER_BLOCK * (DIM / 4); i += 256) {
        const int r = i >> 4;
        const int j = i & 15;
        const float4 v = cb4[(size_t)best_lds[r] * (DIM / 4) + j];
        const size_t g = grow + (size_t)r * (DIM / 4) + j;
        o[g] = v;
        o[g + out1_off] = v;
    }
}

// ---------------------------------------------------------------------------
// MFMA PATH. Round-7: revert to the 16x16 inner loop (round-5: 60 us, VGPR
// 88, zero spill — round-6's 32x32 needed ~160 live regs, allocator capped
// at 128, spilled ~17 MB/dispatch and regressed to 88 us). Add the verified
// 2-rowset structure (32 rows/wave -> halves LDS-read volume, round-5's
// largest cost) and GROUPS=2 (grid 256: B image staged once per CU, not 4x).
// Fixup: 4x wave count — round-6 counters showed nflag ~= 35k rows (27%),
// so fixup throughput, not flag count, is the lever (EPS can't shrink: the
// reference's own ulp(64) rounding ~1.5e-5 dominates the 3e-5 threshold).
// ---------------------------------------------------------------------------
typedef __bf16 bfx8 __attribute__((ext_vector_type(8)));
typedef float  f32x4 __attribute__((ext_vector_type(4)));

#define EPS_GAP 3.0e-5f

// fp32 -> (hi bf16, lo bf16); x-hi exact (Sterbenz), lo = RN(residual).
__device__ __forceinline__ void split_bf16(float x, unsigned short& h, unsigned short& l) {
    unsigned int xb = __float_as_uint(x);
    unsigned int hb = (xb + 0x8000u) & 0xffff0000u;
    h = (unsigned short)(hb >> 16);
    float lf = x - __uint_as_float(hb);
    l = (unsigned short)((__float_as_uint(lf) + 0x8000u) >> 16);
}

// Prep (round-2/5 verified 16x16 pack): slot id = (tile*2 + kstep)*64 + lane;
// elem j of lane l is cb[tile*16 + (l&15)][kstep*32 + (l>>4)*8 + j].
__global__ void vq_prep(const float* __restrict__ cb,
                        unsigned short* __restrict__ wh,
                        unsigned short* __restrict__ wl,
                        float* __restrict__ esq,
                        int* __restrict__ gcnt) {
    const int id = blockIdx.x * 256 + threadIdx.x;      // 0..4095
    if (id == 0) gcnt[0] = 0;
    const int l = id & 63;
    const int s = (id >> 6) & 1;
    const int t = id >> 7;
    const int code = t * 16 + (l & 15);
    const int d0 = s * 32 + (l >> 4) * 8;
    const float* p = cb + (size_t)code * DIM + d0;
    float4 v0 = *(const float4*)p;
    float4 v1 = *(const float4*)(p + 4);
    float f[8] = {v0.x, v0.y, v0.z, v0.w, v1.x, v1.y, v1.z, v1.w};
    union { unsigned short u[8]; uint4 q; } H, L;
#pragma unroll
    for (int j = 0; j < 8; ++j) split_bf16(f[j], H.u[j], L.u[j]);
    *(uint4*)(wh + (size_t)id * 8) = H.q;
    *(uint4*)(wl + (size_t)id * 8) = L.q;
    if (id < K_CODES) esq[id] = np_pairwise_sumsq(cb + (size_t)id * DIM);
}

// Main: 512 threads = 8 waves; per group each wave owns 32 rows (2 rowsets
// of 16); GROUPS=2 sequential groups -> 512 rows/block; grid = n_rows/512
// (256 blocks = 1/CU). B hi+lo staged once in 128 KB LDS. Live set at the
// MFMA cluster ~100-120 VGPR (A 32 + B 16 + acc 8 + state 24 + addr) < 128.
// waves_per_eu(1,2) truthful: 135 KB LDS caps at 1 block/CU = 2 waves/EU.
__global__ __launch_bounds__(512)
__attribute__((amdgpu_waves_per_eu(1, 2))) void vq_mfma_main(
    const float* __restrict__ z,
    const unsigned short* __restrict__ wfrag,   // hi 64KB || lo 64KB
    const float* __restrict__ esq_g,
    const float* __restrict__ cb,
    float* __restrict__ out,
    int* __restrict__ gcnt, int* __restrict__ grows,
    int n_rows) {
    __shared__ unsigned short b_lds[K_CODES * DIM * 2];  // 131072 B
    __shared__ float esq_lds[K_CODES];
    __shared__ int   best_lds[BROWS];

    const int t = threadIdx.x;
    const int wave = t >> 6;
    const int lane = t & 63;
    const int lg = lane >> 4;      // k-group / D-row group
    const int lr = lane & 15;      // A row within set / D col (code)
    const int rb = blockIdx.x * BROWS;

    // Stage the 128 KB fragment image once (16 x 8 KB cooperative copy).
    {
        const uint4* src = (const uint4*)wfrag;
        uint4* dst = (uint4*)b_lds;
#pragma unroll
        for (int i = 0; i < 16; ++i) dst[t + i * 512] = src[t + i * 512];
    }
    if (t < K_CODES) esq_lds[t] = esq_g[t];
    __syncthreads();   // b_lds + esq_lds ready

#pragma unroll 1
    for (int g = 0; g < GROUPS; ++g) {
        const int grb = rb + g * (BROWS / GROUPS) + wave * 32;

        // A fragments (verified round-2/3/4 layout): row = grb + RS*16 + lr,
        // k = s*32 + lg*8 + j. Loaded once per group, kept in VGPRs.
        bfx8 a_hi[2][2], a_lo[2][2];
#pragma unroll
        for (int RS = 0; RS < 2; ++RS) {
#pragma unroll
            for (int s = 0; s < 2; ++s) {
                const float* zp = z + (size_t)(grb + RS * 16 + lr) * DIM + s * 32 + lg * 8;
                float4 v0 = *(const float4*)zp;
                float4 v1 = *(const float4*)(zp + 4);
                float f[8] = {v0.x, v0.y, v0.z, v0.w, v1.x, v1.y, v1.z, v1.w};
                union { unsigned short u[8]; bfx8 b; } H, L;
#pragma unroll
                for (int j = 0; j < 8; ++j) split_bf16(f[j], H.u[j], L.u[j]);
                a_hi[RS][s] = H.b;
                a_lo[RS][s] = L.b;
            }
        }

        float b1[2][4], b2[2][4];
        int   k1[2][4];
#pragma unroll
        for (int RS = 0; RS < 2; ++RS)
#pragma unroll
            for (int i = 0; i < 4; ++i) { b1[RS][i] = INFINITY; b2[RS][i] = INFINITY; k1[RS][i] = 0; }

        for (int tt = 0; tt < 32; ++tt) {
            // B frags from LDS: lane-linear b128 reads (0 conflicts, r5 PMC),
            // shared by both rowsets -> LDS volume per row halves vs r5.
            const int s0 = ((tt * 2 + 0) * 64 + lane) * 8;
            const int s1 = ((tt * 2 + 1) * 64 + lane) * 8;
            bfx8 bh0 = *(const bfx8*)(b_lds + s0);
            bfx8 bh1 = *(const bfx8*)(b_lds + s1);
            bfx8 bl0 = *(const bfx8*)(b_lds + 32768 + s0);
            bfx8 bl1 = *(const bfx8*)(b_lds + 32768 + s1);

            f32x4 acc0 = {0.f, 0.f, 0.f, 0.f};
            f32x4 acc1 = {0.f, 0.f, 0.f, 0.f};
            // zh*eh (2 ksteps) + zh*el + zl*eh — verified 6-MFMA split.
            acc0 = __builtin_amdgcn_mfma_f32_16x16x32_bf16(a_hi[0][0], bh0, acc0, 0, 0, 0);
            acc0 = __builtin_amdgcn_mfma_f32_16x16x32_bf16(a_hi[0][1], bh1, acc0, 0, 0, 0);
            acc0 = __builtin_amdgcn_mfma_f32_16x16x32_bf16(a_hi[0][0], bl0, acc0, 0, 0, 0);
            acc0 = __builtin_amdgcn_mfma_f32_16x16x32_bf16(a_hi[0][1], bl1, acc0, 0, 0, 0);
            acc0 = __builtin_amdgcn_mfma_f32_16x16x32_bf16(a_lo[0][0], bh0, acc0, 0, 0, 0);
            acc0 = __builtin_amdgcn_mfma_f32_16x16x32_bf16(a_lo[0][1], bh1, acc0, 0, 0, 0);
            acc1 = __builtin_amdgcn_mfma_f32_16x16x32_bf16(a_hi[1][0], bh0, acc1, 0, 0, 0);
            acc1 = __builtin_amdgcn_mfma_f32_16x16x32_bf16(a_hi[1][1], bh1, acc1, 0, 0, 0);
            acc1 = __builtin_amdgcn_mfma_f32_16x16x32_bf16(a_hi[1][0], bl0, acc1, 0, 0, 0);
            acc1 = __builtin_amdgcn_mfma_f32_16x16x32_bf16(a_hi[1][1], bl1, acc1, 0, 0, 0);
            acc1 = __builtin_amdgcn_mfma_f32_16x16x32_bf16(a_lo[1][0], bh0, acc1, 0, 0, 0);
            acc1 = __builtin_amdgcn_mfma_f32_16x16x32_bf16(a_lo[1][1], bh1, acc1, 0, 0, 0);

            const float ev = esq_lds[tt * 16 + lr];
            const int   kk = tt * 16 + lr;
#pragma unroll
            for (int i = 0; i < 4; ++i) {
                {
                    float s = fmaf(-2.0f, acc0[i], ev);   // row-constant zsq dropped
                    b2[0][i] = fminf(fmaxf(s, b1[0][i]), b2[0][i]);
                    bool c = s < b1[0][i];
                    b1[0][i] = c ? s : b1[0][i];
                    k1[0][i] = c ? kk : k1[0][i];
                }
                {
                    float s = fmaf(-2.0f, acc1[i], ev);
                    b2[1][i] = fminf(fmaxf(s, b1[1][i]), b2[1][i]);
                    bool c = s < b1[1][i];
                    b1[1][i] = c ? s : b1[1][i];
                    k1[1][i] = c ? kk : k1[1][i];
                }
            }
        }

        // Reduce (b1,k1,b2) across the 16 lanes of each D-row group.
#pragma unroll
        for (int m = 1; m <= 8; m <<= 1) {
#pragma unroll
            for (int RS = 0; RS < 2; ++RS) {
#pragma unroll
                for (int i = 0; i < 4; ++i) {
                    float ob1 = __shfl_xor(b1[RS][i], m);
                    int   ok1 = __shfl_xor(k1[RS][i], m);
                    float ob2 = __shfl_xor(b2[RS][i], m);
                    float nb2 = fminf(fmaxf(b1[RS][i], ob1), fminf(b2[RS][i], ob2));
                    bool take = (ob1 < b1[RS][i]) || (ob1 == b1[RS][i] && ok1 < k1[RS][i]);
                    b1[RS][i] = take ? ob1 : b1[RS][i];
                    k1[RS][i] = take ? ok1 : k1[RS][i];
                    b2[RS][i] = nb2;
                }
            }
        }

        // Publish; flag near-ties into the global fixup list.
        // D layout (verified): col=lane&15 (code), row=(lane>>4)*4+reg.
        if (lr == 0) {
#pragma unroll
            for (int RS = 0; RS < 2; ++RS) {
#pragma unroll
                for (int i = 0; i < 4; ++i) {
                    const int rl = g * (BROWS / GROUPS) + wave * 32 + RS * 16 + lg * 4 + i;
                    best_lds[rl] = k1[RS][i];
                    if (b2[RS][i] - b1[RS][i] <= EPS_GAP) {
                        int p = atomicAdd(gcnt, 1);
                        grows[p] = rb + rl;
                    }
                }
            }
        }
    }
    __syncthreads();

    // Block-cooperative coalesced gather + dual write (verified pattern).
    const float4* cb4 = (const float4*)cb;
    float4* o = (float4*)out;
    const size_t out1_off = (size_t)n_rows * (DIM / 4);
    const size_t grow = (size_t)blockIdx.x * BROWS * (DIM / 4);
#pragma unroll
    for (int i = t; i < BROWS * (DIM / 4); i += 512) {
        const int r = i >> 4;
        const int j = i & 15;
        const float4 v = cb4[(size_t)best_lds[r] * (DIM / 4) + j];
        const size_t g = grow + (size_t)r * (DIM / 4) + j;
        o[g] = v;
        o[g + out1_off] = v;
    }
}

// Fixup (verified rounds 5/6 body): one wave per flagged row; wave-uniform
// scalar z loads; bit-identical np arithmetic. Round-7: grid 1024 (4096
// waves) so the ~35k flagged rows take ~9 rows/wave instead of 34.
__global__ __launch_bounds__(256, 1) void vq_fixup(
    const float* __restrict__ z, const float* __restrict__ cb,
    const float* __restrict__ esq_g,
    const int* __restrict__ gcnt, const int* __restrict__ grows,
    float* __restrict__ out, int n_rows) {
#pragma clang fp contract(off)
    const int lane = threadIdx.x & 63;
    const int wid = (blockIdx.x * 256 + threadIdx.x) >> 6;   // 0..4095
    const int nf = gcnt[0];

    for (int fi = wid; fi < nf; fi += 4096) {
        const int row = __builtin_amdgcn_readfirstlane(grows[fi]);
        const float* zp = z + (size_t)row * DIM;
        float zs[DIM];
#pragma unroll
        for (int j = 0; j < DIM; ++j) zs[j] = zp[j];

        const float zsq = np_pairwise_sumsq(zs);
        float dmin = INFINITY;
        int bk = lane * 8;
        const float* cbase = cb + (size_t)(lane * 8) * DIM;
#pragma unroll
        for (int c = 0; c < 8; ++c) {
            const float dot = np_dot8acc(zs, cbase + (size_t)c * DIM);
            const float tkv = zsq + esq_g[lane * 8 + c];
            const float m2 = 2.0f * dot;
            const float d = tkv - m2;
            if (d < dmin) { dmin = d; bk = lane * 8 + c; }
        }
#pragma unroll
        for (int m = 1; m <= 32; m <<= 1) {
            float od = __shfl_xor(dmin, m);
            int   ob = __shfl_xor(bk, m);
            bool take = (od < dmin) || (od == dmin && ob < bk);
            dmin = take ? od : dmin;
            bk = take ? ob : bk;
        }
        if (lane < 16) {
            const float4 v = ((const float4*)cb)[(size_t)bk * (DIM / 4) + lane];
            float4* o = (float4*)out;
            const size_t g = (size_t)row * (DIM / 4) + lane;
            o[g] = v;
            o[g + (size_t)n_rows * (DIM / 4)] = v;
        }
    }
}

// ---------------------------------------------------------------------------
extern "C" void kernel_launch(void* const* d_in, const int* in_sizes, int n_in,
                              void* d_out, int out_size, void* d_ws, size_t ws_size,
                              hipStream_t stream) {
    const float* z  = (const float*)d_in[0];   // [N, 64] fp32
    const float* cb = (const float*)d_in[1];   // [512, 64] fp32
    float* out = (float*)d_out;                // [2 * N * 64] fp32

    const int n_rows = in_sizes[0] / DIM;      // 131072

    // ws layout: wh 64KB | wl 64KB | esq 2KB | gcnt 16B | grows n_rows*4B
    const size_t frag_elems = (size_t)K_CODES * DIM;           // 32768 shorts
    const size_t WS_NEED = frag_elems * 2 * 2 + K_CODES * 4 + 16 + (size_t)n_rows * 4;
    if (ws_size >= WS_NEED && (n_rows % BROWS) == 0) {
        unsigned short* wh = (unsigned short*)d_ws;
        unsigned short* wl = wh + frag_elems;
        float* esq = (float*)(wl + frag_elems);
        int* gcnt  = (int*)(esq + K_CODES);
        int* grows = gcnt + 4;
        vq_prep<<<dim3(16), dim3(256), 0, stream>>>(cb, wh, wl, esq, gcnt);
        vq_mfma_main<<<dim3(n_rows / BROWS), dim3(512), 0, stream>>>(
            z, wh, esq, cb, out, gcnt, grows, n_rows);
        vq_fixup<<<dim3(1024), dim3(256), 0, stream>>>(
            z, cb, esq, gcnt, grows, out, n_rows);
    } else {
        vq_argmin_gather<<<dim3(n_rows / ROWS_PER_BLOCK), dim3(256), 0, stream>>>(
            z, cb, out, n_rows);
    }
}